// Round 2
// baseline (2774.256 us; speedup 1.0000x reference)
//
#include <hip/hip_runtime.h>

typedef _Float16 half_t;
typedef _Float16 half8 __attribute__((ext_vector_type(8)));
typedef float floatx4 __attribute__((ext_vector_type(4)));

#define NSEQ   256      // B*S
#define TLEN   128
#define EMBD   512
#define UNITSZ 512
#define GC     2048     // 4*UNITS
#define NTOK   32768    // NSEQ*TLEN
#define NCOL   4096     // 2 dirs * GC
#define KDIM   512

// workspace layout (bytes)
constexpr size_t OFF_EMB = 0;                    // emb_f16: NTOK*512*2 = 33,554,432
constexpr size_t OFF_WT  = 33554432;             // WcatT fp16 [4096][512] = 4,194,304
constexpr size_t OFF_UT  = OFF_WT + 4194304;     // UcatT fp16 [4096][512] = 4,194,304
constexpr size_t OFF_HB  = OFF_UT + 4194304;     // hbuf fp16 [2dir][2par][256][512] = 1,048,576
constexpr size_t OFF_CNT = OFF_HB + 1048576;     // counters, 4096 B
constexpr size_t OFF_XW  = OFF_CNT + 4096;       // xW fp16 [32768][4096] = 268,435,456

__device__ inline float sigm(float x)  { return 1.0f / (1.0f + __expf(-x)); }
__device__ inline float tanhx(float x) { return 2.0f / (1.0f + __expf(-2.0f * x)) - 1.0f; }

// ---------------- pack W/U (fp32 [512][2048] per dir) -> transposed fp16 [dir*2048+gcol][512]
__global__ void pack_kernel(const float* __restrict__ Wf, const float* __restrict__ Uf,
                            const float* __restrict__ Wb, const float* __restrict__ Ub,
                            half_t* __restrict__ WT, half_t* __restrict__ UT) {
    int c = blockIdx.x * 256 + threadIdx.x;          // 524288 chunks total
    int arr = c >> 18;                               // 0 = W, 1 = U
    int r = c & 262143;                              // 262144 = 4096*64
    int kc = r >> 12;                                // 64 chunks of 8 k
    int gc = r & 4095;                               // lanes vary gc -> coalesced reads
    int dir = gc >> 11;
    int g = gc & 2047;
    const float* src = (arr == 0) ? (dir ? Wb : Wf) : (dir ? Ub : Uf);
    half_t* dst = (arr == 0) ? WT : UT;
    half8 v;
#pragma unroll
    for (int j = 0; j < 8; ++j)
        v[j] = (half_t)src[(size_t)(kc * 8 + j) * GC + g];
    *(half8*)(dst + (size_t)gc * KDIM + kc * 8) = v;
}

// ---------------- zero hbuf + counters
__global__ void zero_kernel(unsigned* __restrict__ hb_and_cnt) {
    int i = blockIdx.x * 256 + threadIdx.x;          // 263168 dwords
    if (i < 263168) hb_and_cnt[i] = 0u;
}

// ---------------- gather: emb_f16[token][512] = fp16(emb_table[x[token]][:])
__global__ void gather_kernel(const int* __restrict__ x, const float* __restrict__ tab,
                              half_t* __restrict__ embf) {
    int g = blockIdx.x * 256 + threadIdx.x;          // 2,097,152 chunks of 8
    int token = g >> 6;
    int k = (g & 63) * 8;
    int id = x[token];
    const float* s = tab + (size_t)id * EMBD + k;
    float4 a = *(const float4*)(s);
    float4 b = *(const float4*)(s + 4);
    half8 v;
    v[0] = (half_t)a.x; v[1] = (half_t)a.y; v[2] = (half_t)a.z; v[3] = (half_t)a.w;
    v[4] = (half_t)b.x; v[5] = (half_t)b.y; v[6] = (half_t)b.z; v[7] = (half_t)b.w;
    *(half8*)(embf + (size_t)token * EMBD + k) = v;
}

// ---------------- GEMM: xW[32768][4096] = emb_f16 @ WcatT^T + bias, fp16 out
__global__ __launch_bounds__(256, 2) void gemm_kernel(const half_t* __restrict__ embf,
                                                      const half_t* __restrict__ WT,
                                                      const float* __restrict__ bf,
                                                      const float* __restrict__ bb,
                                                      half_t* __restrict__ xw) {
    __shared__ half_t As[128 * 40];   // [row][32+8pad]
    __shared__ half_t Bs[128 * 40];   // B^T tile: [col][32+8pad]
    int bx = blockIdx.x;
    int bm = bx & 255, bn = bx >> 8;
    int r0 = bm * 128, c0 = bn * 128;
    int tid = threadIdx.x;
    int w = tid >> 6, l = tid & 63;
    int q = l >> 4, cl = l & 15;
    int mq = (w >> 1) * 64, nq = (w & 1) * 64;

    floatx4 acc[4][4];
#pragma unroll
    for (int a = 0; a < 4; ++a)
#pragma unroll
        for (int b = 0; b < 4; ++b) acc[a][b] = (floatx4){0.f, 0.f, 0.f, 0.f};

    for (int kb = 0; kb < 16; ++kb) {
#pragma unroll
        for (int cc = 0; cc < 2; ++cc) {
            int c = tid + cc * 256;
            int row = c >> 2, qt = c & 3;
            half8 va = *(const half8*)(embf + (size_t)(r0 + row) * KDIM + kb * 32 + qt * 8);
            *(half8*)(As + row * 40 + qt * 8) = va;
            half8 vb = *(const half8*)(WT + (size_t)(c0 + row) * KDIM + kb * 32 + qt * 8);
            *(half8*)(Bs + row * 40 + qt * 8) = vb;
        }
        __syncthreads();
        half8 af[4], bfr[4];
#pragma unroll
        for (int mb = 0; mb < 4; ++mb)
            af[mb] = *(const half8*)(As + (mq + mb * 16 + cl) * 40 + q * 8);
#pragma unroll
        for (int nb = 0; nb < 4; ++nb)
            bfr[nb] = *(const half8*)(Bs + (nq + nb * 16 + cl) * 40 + q * 8);
#pragma unroll
        for (int mb = 0; mb < 4; ++mb)
#pragma unroll
            for (int nb = 0; nb < 4; ++nb)
                acc[mb][nb] = __builtin_amdgcn_mfma_f32_16x16x32_f16(af[mb], bfr[nb], acc[mb][nb], 0, 0, 0);
        __syncthreads();
    }
    // epilogue: + bias, store fp16
#pragma unroll
    for (int nb = 0; nb < 4; ++nb) {
        int col = c0 + nq + nb * 16 + cl;
        int dir = col >> 11, gcol = col & 2047;
        float bias = dir ? bb[gcol] : bf[gcol];
#pragma unroll
        for (int mb = 0; mb < 4; ++mb) {
#pragma unroll
            for (int r = 0; r < 4; ++r) {
                int row = r0 + mq + mb * 16 + q * 4 + r;
                xw[(size_t)row * NCOL + col] = (half_t)(acc[mb][nb][r] + bias);
            }
        }
    }
}

// ---------------- persistent bidirectional LSTM (plain launch; 256 blocks x 256 thr,
// co-residency by construction: 1 block/CU min occupancy, grid == CU count.
// Cross-WG sync = device-scope atomic counter per 8-WG row-group; no grid.sync()
// is used, so cooperative launch is unnecessary (and it failed silently in R1).
__global__ __launch_bounds__(256, 1) void lstm_kernel(const half_t* __restrict__ xw,
                                                      const half_t* __restrict__ UT,
                                                      half_t* __restrict__ hbuf,
                                                      const int* __restrict__ x,
                                                      float* __restrict__ out,
                                                      unsigned* __restrict__ cnt) {
    __shared__ half_t Ast[8192];   // 16 kk * 64 lanes * 8 halves, MFMA-frag order
    int bx = blockIdx.x;
    int dir = bx >> 7;
    int rowg = (bx >> 3) & 15;
    int wgc = bx & 7;
    int tid = threadIdx.x;
    int w = tid >> 6, l = tid & 63;
    int q = l >> 4, cl = l & 15;
    int cg = wgc * 4 + w;           // col-group 0..31
    int ub = cg * 16;               // unit base
    int r0 = rowg * 16;             // sequence-row base

    // preload U B-frags into registers: bfrag[kk*4+cf], cf = gate
    half8 bfrag[64];
#pragma unroll
    for (int kk = 0; kk < 16; ++kk)
#pragma unroll
        for (int cf = 0; cf < 4; ++cf)
            bfrag[kk * 4 + cf] = *(const half8*)(UT + (size_t)(dir * 2048 + cf * 512 + ub + cl) * KDIM + kk * 32 + q * 8);

    float cs[4] = {0.f, 0.f, 0.f, 0.f};
    float hs[4] = {0.f, 0.f, 0.f, 0.f};
    unsigned* cptr = cnt + (dir * 16 + rowg) * 16;   // 64B-strided counters

#pragma unroll 1
    for (int t = 0; t < TLEN; ++t) {
        int tIdx = dir ? (127 - t) : t;
        int rpar = t & 1, wpar = rpar ^ 1;
        if (t > 0) {
            if (tid == 0) {
                while (__hip_atomic_load(cptr, __ATOMIC_RELAXED, __HIP_MEMORY_SCOPE_AGENT) < (unsigned)(8 * t))
                    __builtin_amdgcn_s_sleep(1);
            }
            __syncthreads();
            __builtin_amdgcn_fence(__ATOMIC_ACQUIRE, "agent");
        }
        // stage h rows r0..r0+15 into LDS in frag order
        const half_t* hsrc = hbuf + (size_t)(dir * 2 + rpar) * NSEQ * UNITSZ;
#pragma unroll
        for (int cc = 0; cc < 4; ++cc) {
            int c = tid + cc * 256;            // 1024 chunks of 16B
            int kk = c >> 6, ll = c & 63;
            int m = ll & 15, koff = kk * 32 + (ll >> 4) * 8;
            half8 v = *(const half8*)(hsrc + (size_t)(r0 + m) * UNITSZ + koff);
            *(half8*)(Ast + c * 8) = v;
        }
        __syncthreads();
        // acc init from xW (bias already baked in)
        floatx4 a0, a1, a2, a3;
        int colb = dir * 2048 + ub + cl;
#pragma unroll
        for (int r = 0; r < 4; ++r) {
            int n = r0 + q * 4 + r;
            size_t ro = ((size_t)n * TLEN + tIdx) * NCOL;
            a0[r] = (float)xw[ro + colb];
            a1[r] = (float)xw[ro + colb + 512];
            a2[r] = (float)xw[ro + colb + 1024];
            a3[r] = (float)xw[ro + colb + 1536];
        }
        // z += h @ U
#pragma unroll
        for (int kk = 0; kk < 16; ++kk) {
            half8 af = *(const half8*)(Ast + (kk * 64 + l) * 8);
            a0 = __builtin_amdgcn_mfma_f32_16x16x32_f16(af, bfrag[kk * 4 + 0], a0, 0, 0, 0);
            a1 = __builtin_amdgcn_mfma_f32_16x16x32_f16(af, bfrag[kk * 4 + 1], a1, 0, 0, 0);
            a2 = __builtin_amdgcn_mfma_f32_16x16x32_f16(af, bfrag[kk * 4 + 2], a2, 0, 0, 0);
            a3 = __builtin_amdgcn_mfma_f32_16x16x32_f16(af, bfrag[kk * 4 + 3], a3, 0, 0, 0);
        }
        // gates + masked state update (lane-local), store h_new
        half_t* hdst = hbuf + (size_t)(dir * 2 + wpar) * NSEQ * UNITSZ;
#pragma unroll
        for (int r = 0; r < 4; ++r) {
            int n = r0 + q * 4 + r;
            int id = x[n * TLEN + tIdx];
            float iv = sigm(a0[r]);
            float fv = sigm(a1[r]);
            float gv = tanhx(a2[r]);
            float ov = sigm(a3[r]);
            float cn = fv * cs[r] + iv * gv;
            float hn = ov * tanhx(cn);
            if (id != 0) { cs[r] = cn; hs[r] = hn; }
            hdst[(size_t)n * UNITSZ + ub + cl] = (half_t)hs[r];
        }
        __syncthreads();   // all waves' stores issued before signal
        if (tid == 0) {
            __threadfence();
            atomicAdd(cptr, 1u);
        }
    }
    // final output: out[n][dir*512 + unit]
#pragma unroll
    for (int r = 0; r < 4; ++r) {
        int n = r0 + q * 4 + r;
        out[(size_t)n * 1024 + dir * 512 + ub + cl] = hs[r];
    }
}

extern "C" void kernel_launch(void* const* d_in, const int* in_sizes, int n_in,
                              void* d_out, int out_size, void* d_ws, size_t ws_size,
                              hipStream_t stream) {
    const int*   x    = (const int*)d_in[0];
    const float* tab  = (const float*)d_in[1];
    const float* Wf   = (const float*)d_in[2];
    const float* Uf   = (const float*)d_in[3];
    const float* bf   = (const float*)d_in[4];
    const float* Wb   = (const float*)d_in[5];
    const float* Ub   = (const float*)d_in[6];
    const float* bb   = (const float*)d_in[7];
    float* out = (float*)d_out;

    char* ws = (char*)d_ws;
    half_t*   embf = (half_t*)(ws + OFF_EMB);
    half_t*   WT   = (half_t*)(ws + OFF_WT);
    half_t*   UT   = (half_t*)(ws + OFF_UT);
    half_t*   hbuf = (half_t*)(ws + OFF_HB);
    unsigned* cnt  = (unsigned*)(ws + OFF_CNT);
    half_t*   xw   = (half_t*)(ws + OFF_XW);
    unsigned* hbz  = (unsigned*)(ws + OFF_HB);   // zero range covers hbuf + cnt (contiguous)

    pack_kernel<<<2048, 256, 0, stream>>>(Wf, Uf, Wb, Ub, WT, UT);
    zero_kernel<<<1028, 256, 0, stream>>>(hbz);
    gather_kernel<<<8192, 256, 0, stream>>>(x, tab, embf);
    gemm_kernel<<<8192, 256, 0, stream>>>(embf, WT, bf, bb, xw);
    lstm_kernel<<<256, 256, 0, stream>>>(xw, UT, hbuf, x, out, cnt);
}

// Round 3
// 1156.847 us; speedup vs baseline: 2.3981x; 2.3981x over previous
//
#include <hip/hip_runtime.h>

typedef _Float16 half_t;
typedef _Float16 half8 __attribute__((ext_vector_type(8)));
typedef float floatx4 __attribute__((ext_vector_type(4)));

#define NSEQ   256      // B*S
#define TLEN   128
#define EMBD   512
#define UNITSZ 512
#define GC     2048     // 4*UNITS
#define NTOK   32768    // NSEQ*TLEN
#define NCOL   4096     // 2 dirs * GC
#define KDIM   512

// workspace layout (bytes)
constexpr size_t OFF_EMB = 0;                    // emb_f16: NTOK*512*2 = 33,554,432
constexpr size_t OFF_WT  = 33554432;             // WcatT fp16 [4096][512] = 4,194,304
constexpr size_t OFF_UT  = OFF_WT + 4194304;     // UcatT fp16 [4096][512] = 4,194,304
constexpr size_t OFF_HB  = OFF_UT + 4194304;     // hbuf fp16 [2dir][2par][256][512] = 1,048,576
constexpr size_t OFF_CNT = OFF_HB + 1048576;     // counters, 4096 B
constexpr size_t OFF_XW  = OFF_CNT + 4096;       // xW fp16 [32768][4096] = 268,435,456

__device__ inline float sigm(float x)  { return 1.0f / (1.0f + __expf(-x)); }
__device__ inline float tanhx(float x) { return 2.0f / (1.0f + __expf(-2.0f * x)) - 1.0f; }

// coherent (agent-scope, sc1: bypass non-coherent L1/L2) 8B load/store
__device__ inline unsigned long long ld8c(const void* p) {
    return __hip_atomic_load((const unsigned long long*)p, __ATOMIC_RELAXED, __HIP_MEMORY_SCOPE_AGENT);
}
__device__ inline void st8c(void* p, unsigned long long v) {
    __hip_atomic_store((unsigned long long*)p, v, __ATOMIC_RELAXED, __HIP_MEMORY_SCOPE_AGENT);
}

// ---------------- pack W/U (fp32 [512][2048] per dir) -> transposed fp16 [dir*2048+gcol][512]
__global__ void pack_kernel(const float* __restrict__ Wf, const float* __restrict__ Uf,
                            const float* __restrict__ Wb, const float* __restrict__ Ub,
                            half_t* __restrict__ WT, half_t* __restrict__ UT) {
    int c = blockIdx.x * 256 + threadIdx.x;          // 524288 chunks total
    int arr = c >> 18;                               // 0 = W, 1 = U
    int r = c & 262143;                              // 262144 = 4096*64
    int kc = r >> 12;                                // 64 chunks of 8 k
    int gc = r & 4095;                               // lanes vary gc -> coalesced reads
    int dir = gc >> 11;
    int g = gc & 2047;
    const float* src = (arr == 0) ? (dir ? Wb : Wf) : (dir ? Ub : Uf);
    half_t* dst = (arr == 0) ? WT : UT;
    half8 v;
#pragma unroll
    for (int j = 0; j < 8; ++j)
        v[j] = (half_t)src[(size_t)(kc * 8 + j) * GC + g];
    *(half8*)(dst + (size_t)gc * KDIM + kc * 8) = v;
}

// ---------------- zero hbuf + counters
__global__ void zero_kernel(unsigned* __restrict__ hb_and_cnt) {
    int i = blockIdx.x * 256 + threadIdx.x;          // 263168 dwords
    if (i < 263168) hb_and_cnt[i] = 0u;
}

// ---------------- gather: emb_f16[token][512] = fp16(emb_table[x[token]][:])
__global__ void gather_kernel(const int* __restrict__ x, const float* __restrict__ tab,
                              half_t* __restrict__ embf) {
    int g = blockIdx.x * 256 + threadIdx.x;          // 2,097,152 chunks of 8
    int token = g >> 6;
    int k = (g & 63) * 8;
    int id = x[token];
    const float* s = tab + (size_t)id * EMBD + k;
    float4 a = *(const float4*)(s);
    float4 b = *(const float4*)(s + 4);
    half8 v;
    v[0] = (half_t)a.x; v[1] = (half_t)a.y; v[2] = (half_t)a.z; v[3] = (half_t)a.w;
    v[4] = (half_t)b.x; v[5] = (half_t)b.y; v[6] = (half_t)b.z; v[7] = (half_t)b.w;
    *(half8*)(embf + (size_t)token * EMBD + k) = v;
}

// ---------------- GEMM: xW[32768][4096] = emb_f16 @ WcatT^T + bias, fp16 out
__global__ __launch_bounds__(256, 2) void gemm_kernel(const half_t* __restrict__ embf,
                                                      const half_t* __restrict__ WT,
                                                      const float* __restrict__ bf,
                                                      const float* __restrict__ bb,
                                                      half_t* __restrict__ xw) {
    __shared__ half_t As[128 * 40];   // [row][32+8pad]
    __shared__ half_t Bs[128 * 40];   // B^T tile: [col][32+8pad]
    int bx = blockIdx.x;
    int bm = bx & 255, bn = bx >> 8;
    int r0 = bm * 128, c0 = bn * 128;
    int tid = threadIdx.x;
    int w = tid >> 6, l = tid & 63;
    int q = l >> 4, cl = l & 15;
    int mq = (w >> 1) * 64, nq = (w & 1) * 64;

    floatx4 acc[4][4];
#pragma unroll
    for (int a = 0; a < 4; ++a)
#pragma unroll
        for (int b = 0; b < 4; ++b) acc[a][b] = (floatx4){0.f, 0.f, 0.f, 0.f};

    for (int kb = 0; kb < 16; ++kb) {
#pragma unroll
        for (int cc = 0; cc < 2; ++cc) {
            int c = tid + cc * 256;
            int row = c >> 2, qt = c & 3;
            half8 va = *(const half8*)(embf + (size_t)(r0 + row) * KDIM + kb * 32 + qt * 8);
            *(half8*)(As + row * 40 + qt * 8) = va;
            half8 vb = *(const half8*)(WT + (size_t)(c0 + row) * KDIM + kb * 32 + qt * 8);
            *(half8*)(Bs + row * 40 + qt * 8) = vb;
        }
        __syncthreads();
        half8 af[4], bfr[4];
#pragma unroll
        for (int mb = 0; mb < 4; ++mb)
            af[mb] = *(const half8*)(As + (mq + mb * 16 + cl) * 40 + q * 8);
#pragma unroll
        for (int nb = 0; nb < 4; ++nb)
            bfr[nb] = *(const half8*)(Bs + (nq + nb * 16 + cl) * 40 + q * 8);
#pragma unroll
        for (int mb = 0; mb < 4; ++mb)
#pragma unroll
            for (int nb = 0; nb < 4; ++nb)
                acc[mb][nb] = __builtin_amdgcn_mfma_f32_16x16x32_f16(af[mb], bfr[nb], acc[mb][nb], 0, 0, 0);
        __syncthreads();
    }
    // epilogue: + bias, store fp16
#pragma unroll
    for (int nb = 0; nb < 4; ++nb) {
        int col = c0 + nq + nb * 16 + cl;
        int dir = col >> 11, gcol = col & 2047;
        float bias = dir ? bb[gcol] : bf[gcol];
#pragma unroll
        for (int mb = 0; mb < 4; ++mb) {
#pragma unroll
            for (int r = 0; r < 4; ++r) {
                int row = r0 + mq + mb * 16 + q * 4 + r;
                xw[(size_t)row * NCOL + col] = (half_t)(acc[mb][nb][r] + bias);
            }
        }
    }
}

// ---------------- persistent bidirectional LSTM (plain launch, 256 blocks x 256 thr).
// Cross-WG h exchange uses agent-scope RELAXED atomics (sc1, bypass non-coherent
// L1/L2) -> NO buffer_wbl2 / buffer_inv fences per step (R2's 18.7us/step killer).
// Release = s_waitcnt vmcnt(0) (stores are write-through) + relaxed atomicAdd.
__global__ __launch_bounds__(256, 1) void lstm_kernel(const half_t* __restrict__ xw,
                                                      const half_t* __restrict__ UT,
                                                      half_t* __restrict__ hbuf,
                                                      const int* __restrict__ x,
                                                      float* __restrict__ out,
                                                      unsigned* __restrict__ cnt) {
    __shared__ half_t Ast[8192];   // 16 kk * 64 lanes * 8 halves, MFMA-frag order
    __shared__ half_t Pk[1024];    // h repack: [16 rows][64 units]
    int bx = blockIdx.x;
    int dir = bx >> 7;
    int rowg = (bx >> 3) & 15;
    int wgc = bx & 7;
    int tid = threadIdx.x;
    int w = tid >> 6, l = tid & 63;
    int q = l >> 4, cl = l & 15;
    int cg = wgc * 4 + w;           // col-group 0..31
    int ub = cg * 16;               // unit base (per wave)
    int ub0 = wgc * 64;             // unit base (per WG)
    int r0 = rowg * 16;             // sequence-row base

    // preload U B-frags into registers: bfrag[kk*4+cf], cf = gate
    half8 bfrag[64];
#pragma unroll
    for (int kk = 0; kk < 16; ++kk)
#pragma unroll
        for (int cf = 0; cf < 4; ++cf)
            bfrag[kk * 4 + cf] = *(const half8*)(UT + (size_t)(dir * 2048 + cf * 512 + ub + cl) * KDIM + kk * 32 + q * 8);

    float cs[4] = {0.f, 0.f, 0.f, 0.f};
    float hs[4] = {0.f, 0.f, 0.f, 0.f};
    unsigned* cptr = cnt + (dir * 16 + rowg) * 16;   // 64B-strided counters
    int colb = dir * 2048 + ub + cl;

    // prefetch xW for t=0 (bias already baked in)
    half_t xv[4][4];
    {
        int tIdx = dir ? 127 : 0;
#pragma unroll
        for (int r = 0; r < 4; ++r) {
            size_t ro = ((size_t)(r0 + q * 4 + r) * TLEN + tIdx) * NCOL;
#pragma unroll
            for (int g = 0; g < 4; ++g)
                xv[g][r] = xw[ro + colb + g * 512];
        }
    }

#pragma unroll 1
    for (int t = 0; t < TLEN; ++t) {
        int tIdx = dir ? (127 - t) : t;
        int rpar = t & 1, wpar = rpar ^ 1;
        if (t > 0) {
            if (tid == 0) {
                while (__hip_atomic_load(cptr, __ATOMIC_RELAXED, __HIP_MEMORY_SCOPE_AGENT) < (unsigned)(32 * t))
                    __builtin_amdgcn_s_sleep(1);
            }
            __syncthreads();
        }
        // stage h rows r0..r0+15 into LDS in frag order (coherent 8B loads)
        const half_t* hsrc = hbuf + (size_t)(dir * 2 + rpar) * NSEQ * UNITSZ;
#pragma unroll
        for (int cc = 0; cc < 4; ++cc) {
            int c = tid + cc * 256;            // 1024 chunks of 16B
            int kk = c >> 6, ll = c & 63;
            int m = ll & 15, koff = kk * 32 + (ll >> 4) * 8;
            const half_t* sp = hsrc + (size_t)(r0 + m) * UNITSZ + koff;
            union { unsigned long long u[2]; half8 v; } cv;
            cv.u[0] = ld8c(sp);
            cv.u[1] = ld8c(sp + 4);
            *(half8*)(Ast + c * 8) = cv.v;
        }
        __syncthreads();
        // acc init from prefetched xW
        floatx4 a0, a1, a2, a3;
#pragma unroll
        for (int r = 0; r < 4; ++r) {
            a0[r] = (float)xv[0][r];
            a1[r] = (float)xv[1][r];
            a2[r] = (float)xv[2][r];
            a3[r] = (float)xv[3][r];
        }
        // prefetch next step's xW (independent of h -> overlaps MFMA + sync)
        if (t + 1 < TLEN) {
            int tN = dir ? (126 - t) : (t + 1);
#pragma unroll
            for (int r = 0; r < 4; ++r) {
                size_t ro = ((size_t)(r0 + q * 4 + r) * TLEN + tN) * NCOL;
#pragma unroll
                for (int g = 0; g < 4; ++g)
                    xv[g][r] = xw[ro + colb + g * 512];
            }
        }
        // z += h @ U
#pragma unroll
        for (int kk = 0; kk < 16; ++kk) {
            half8 af = *(const half8*)(Ast + (kk * 64 + l) * 8);
            a0 = __builtin_amdgcn_mfma_f32_16x16x32_f16(af, bfrag[kk * 4 + 0], a0, 0, 0, 0);
            a1 = __builtin_amdgcn_mfma_f32_16x16x32_f16(af, bfrag[kk * 4 + 1], a1, 0, 0, 0);
            a2 = __builtin_amdgcn_mfma_f32_16x16x32_f16(af, bfrag[kk * 4 + 2], a2, 0, 0, 0);
            a3 = __builtin_amdgcn_mfma_f32_16x16x32_f16(af, bfrag[kk * 4 + 3], a3, 0, 0, 0);
        }
        // gates + masked state update (lane-local), repack h into LDS
#pragma unroll
        for (int r = 0; r < 4; ++r) {
            int n = r0 + q * 4 + r;
            int id = x[n * TLEN + tIdx];
            float iv = sigm(a0[r]);
            float fv = sigm(a1[r]);
            float gv = tanhx(a2[r]);
            float ov = sigm(a3[r]);
            float cn = fv * cs[r] + iv * gv;
            float hn = ov * tanhx(cn);
            if (id != 0) { cs[r] = cn; hs[r] = hn; }
            Pk[(q * 4 + r) * 64 + w * 16 + cl] = (half_t)hs[r];
        }
        __syncthreads();
        // packed coherent store: 1 x 8B per thread (16 rows x 64 units x 2B = 2KB/WG)
        half_t* hdst = hbuf + (size_t)(dir * 2 + wpar) * NSEQ * UNITSZ;
        {
            int prow = tid >> 4, pch = tid & 15;
            unsigned long long pv = *(const unsigned long long*)(Pk + prow * 64 + pch * 4);
            st8c(hdst + (size_t)(r0 + prow) * UNITSZ + ub0 + pch * 4, pv);
        }
        // hand-rolled release: stores are sc1 write-through -> vmcnt drain suffices
        asm volatile("s_waitcnt vmcnt(0)" ::: "memory");
        if (l == 0)
            __hip_atomic_fetch_add(cptr, 1u, __ATOMIC_RELAXED, __HIP_MEMORY_SCOPE_AGENT);
    }
    // final output: out[n][dir*512 + unit]
#pragma unroll
    for (int r = 0; r < 4; ++r) {
        int n = r0 + q * 4 + r;
        out[(size_t)n * 1024 + dir * 512 + ub + cl] = hs[r];
    }
}

extern "C" void kernel_launch(void* const* d_in, const int* in_sizes, int n_in,
                              void* d_out, int out_size, void* d_ws, size_t ws_size,
                              hipStream_t stream) {
    const int*   x    = (const int*)d_in[0];
    const float* tab  = (const float*)d_in[1];
    const float* Wf   = (const float*)d_in[2];
    const float* Uf   = (const float*)d_in[3];
    const float* bf   = (const float*)d_in[4];
    const float* Wb   = (const float*)d_in[5];
    const float* Ub   = (const float*)d_in[6];
    const float* bb   = (const float*)d_in[7];
    float* out = (float*)d_out;

    char* ws = (char*)d_ws;
    half_t*   embf = (half_t*)(ws + OFF_EMB);
    half_t*   WT   = (half_t*)(ws + OFF_WT);
    half_t*   UT   = (half_t*)(ws + OFF_UT);
    half_t*   hbuf = (half_t*)(ws + OFF_HB);
    unsigned* cnt  = (unsigned*)(ws + OFF_CNT);
    half_t*   xw   = (half_t*)(ws + OFF_XW);
    unsigned* hbz  = (unsigned*)(ws + OFF_HB);   // zero range covers hbuf + cnt (contiguous)

    pack_kernel<<<2048, 256, 0, stream>>>(Wf, Uf, Wb, Ub, WT, UT);
    zero_kernel<<<1028, 256, 0, stream>>>(hbz);
    gather_kernel<<<8192, 256, 0, stream>>>(x, tab, embf);
    gemm_kernel<<<8192, 256, 0, stream>>>(embf, WT, bf, bb, xw);
    lstm_kernel<<<256, 256, 0, stream>>>(xw, UT, hbuf, x, out, cnt);
}

// Round 4
// 1106.253 us; speedup vs baseline: 2.5078x; 1.0457x over previous
//
#include <hip/hip_runtime.h>

typedef _Float16 half_t;
typedef _Float16 half8 __attribute__((ext_vector_type(8)));
typedef float floatx4 __attribute__((ext_vector_type(4)));

#define NSEQ   256      // B*S
#define TLEN   128
#define EMBD   512
#define UNITSZ 512
#define GC     2048     // 4*UNITS
#define NTOK   32768    // NSEQ*TLEN
#define NCOL   4096     // 2 dirs * GC
#define KDIM   512

// workspace layout (bytes)
constexpr size_t OFF_EMB = 0;                    // emb_f16: NTOK*512*2 = 33,554,432
constexpr size_t OFF_WT  = 33554432;             // WcatT fp16 [4096][512] = 4,194,304
constexpr size_t OFF_UT  = OFF_WT + 4194304;     // UcatT fp16 [4096][512] = 4,194,304
constexpr size_t OFF_HB  = OFF_UT + 4194304;     // hbuf fp16 [2dir][2par][256][512] = 1,048,576
constexpr size_t OFF_CNT = OFF_HB + 1048576;     // counters, 4096 B
constexpr size_t OFF_MSK = OFF_CNT + 4096;       // mask bits: 256 * 2 u64 = 4096 B
constexpr size_t OFF_XW  = OFF_MSK + 4096;       // xW fp16 [32768][4096] = 268,435,456

__device__ inline float sigm(float x)  { return 1.0f / (1.0f + __expf(-x)); }
__device__ inline float tanhx(float x) { return 2.0f / (1.0f + __expf(-2.0f * x)) - 1.0f; }

// coherent (agent-scope, bypass non-coherent L1/L2) 8B load/store
__device__ inline unsigned long long ld8c(const void* p) {
    return __hip_atomic_load((const unsigned long long*)p, __ATOMIC_RELAXED, __HIP_MEMORY_SCOPE_AGENT);
}
__device__ inline void st8c(void* p, unsigned long long v) {
    __hip_atomic_store((unsigned long long*)p, v, __ATOMIC_RELAXED, __HIP_MEMORY_SCOPE_AGENT);
}

// ---------------- pack W/U (fp32 [512][2048] per dir) -> transposed fp16 [dir*2048+gcol][512]
__global__ void pack_kernel(const float* __restrict__ Wf, const float* __restrict__ Uf,
                            const float* __restrict__ Wb, const float* __restrict__ Ub,
                            half_t* __restrict__ WT, half_t* __restrict__ UT) {
    int c = blockIdx.x * 256 + threadIdx.x;          // 524288 chunks total
    int arr = c >> 18;                               // 0 = W, 1 = U
    int r = c & 262143;                              // 262144 = 4096*64
    int kc = r >> 12;                                // 64 chunks of 8 k
    int gc = r & 4095;                               // lanes vary gc -> coalesced reads
    int dir = gc >> 11;
    int g = gc & 2047;
    const float* src = (arr == 0) ? (dir ? Wb : Wf) : (dir ? Ub : Uf);
    half_t* dst = (arr == 0) ? WT : UT;
    half8 v;
#pragma unroll
    for (int j = 0; j < 8; ++j)
        v[j] = (half_t)src[(size_t)(kc * 8 + j) * GC + g];
    *(half8*)(dst + (size_t)gc * KDIM + kc * 8) = v;
}

// ---------------- zero hbuf + counters
__global__ void zero_kernel(unsigned* __restrict__ hb_and_cnt) {
    int i = blockIdx.x * 256 + threadIdx.x;          // 263168 dwords
    if (i < 263168) hb_and_cnt[i] = 0u;
}

// ---------------- pack per-row validity masks: mk[n] = 128 bits of (x!=0)
__global__ void mask_kernel(const int* __restrict__ x, unsigned long long* __restrict__ mk) {
    int n = blockIdx.x;       // 256 blocks x 64 threads
    int l = threadIdx.x;
    unsigned long long b0 = __ballot(x[n * TLEN + l] != 0);
    unsigned long long b1 = __ballot(x[n * TLEN + 64 + l] != 0);
    if (l == 0) { mk[n * 2] = b0; mk[n * 2 + 1] = b1; }
}

// ---------------- gather: emb_f16[token][512] = fp16(emb_table[x[token]][:])
__global__ void gather_kernel(const int* __restrict__ x, const float* __restrict__ tab,
                              half_t* __restrict__ embf) {
    int g = blockIdx.x * 256 + threadIdx.x;          // 2,097,152 chunks of 8
    int token = g >> 6;
    int k = (g & 63) * 8;
    int id = x[token];
    const float* s = tab + (size_t)id * EMBD + k;
    float4 a = *(const float4*)(s);
    float4 b = *(const float4*)(s + 4);
    half8 v;
    v[0] = (half_t)a.x; v[1] = (half_t)a.y; v[2] = (half_t)a.z; v[3] = (half_t)a.w;
    v[4] = (half_t)b.x; v[5] = (half_t)b.y; v[6] = (half_t)b.z; v[7] = (half_t)b.w;
    *(half8*)(embf + (size_t)token * EMBD + k) = v;
}

// ---------------- GEMM: xW[32768][4096] = emb_f16 @ WcatT^T + bias, fp16 out
__global__ __launch_bounds__(256, 2) void gemm_kernel(const half_t* __restrict__ embf,
                                                      const half_t* __restrict__ WT,
                                                      const float* __restrict__ bf,
                                                      const float* __restrict__ bb,
                                                      half_t* __restrict__ xw) {
    __shared__ half_t As[128 * 40];   // [row][32+8pad]
    __shared__ half_t Bs[128 * 40];   // B^T tile: [col][32+8pad]
    int bx = blockIdx.x;
    int bm = bx & 255, bn = bx >> 8;
    int r0 = bm * 128, c0 = bn * 128;
    int tid = threadIdx.x;
    int w = tid >> 6, l = tid & 63;
    int q = l >> 4, cl = l & 15;
    int mq = (w >> 1) * 64, nq = (w & 1) * 64;

    floatx4 acc[4][4];
#pragma unroll
    for (int a = 0; a < 4; ++a)
#pragma unroll
        for (int b = 0; b < 4; ++b) acc[a][b] = (floatx4){0.f, 0.f, 0.f, 0.f};

    for (int kb = 0; kb < 16; ++kb) {
#pragma unroll
        for (int cc = 0; cc < 2; ++cc) {
            int c = tid + cc * 256;
            int row = c >> 2, qt = c & 3;
            half8 va = *(const half8*)(embf + (size_t)(r0 + row) * KDIM + kb * 32 + qt * 8);
            *(half8*)(As + row * 40 + qt * 8) = va;
            half8 vb = *(const half8*)(WT + (size_t)(c0 + row) * KDIM + kb * 32 + qt * 8);
            *(half8*)(Bs + row * 40 + qt * 8) = vb;
        }
        __syncthreads();
        half8 af[4], bfr[4];
#pragma unroll
        for (int mb = 0; mb < 4; ++mb)
            af[mb] = *(const half8*)(As + (mq + mb * 16 + cl) * 40 + q * 8);
#pragma unroll
        for (int nb = 0; nb < 4; ++nb)
            bfr[nb] = *(const half8*)(Bs + (nq + nb * 16 + cl) * 40 + q * 8);
#pragma unroll
        for (int mb = 0; mb < 4; ++mb)
#pragma unroll
            for (int nb = 0; nb < 4; ++nb)
                acc[mb][nb] = __builtin_amdgcn_mfma_f32_16x16x32_f16(af[mb], bfr[nb], acc[mb][nb], 0, 0, 0);
        __syncthreads();
    }
    // epilogue: + bias, store fp16
#pragma unroll
    for (int nb = 0; nb < 4; ++nb) {
        int col = c0 + nq + nb * 16 + cl;
        int dir = col >> 11, gcol = col & 2047;
        float bias = dir ? bb[gcol] : bf[gcol];
#pragma unroll
        for (int mb = 0; mb < 4; ++mb) {
#pragma unroll
            for (int r = 0; r < 4; ++r) {
                int row = r0 + mq + mb * 16 + q * 4 + r;
                xw[(size_t)row * NCOL + col] = (half_t)(acc[mb][nb][r] + bias);
            }
        }
    }
}

// ---------------- persistent bidirectional LSTM (plain launch, 256 blocks x 256 thr).
// Step order matters: pack-store -> vmcnt(0) (drains ONLY that 8B store) ->
// signal -> THEN issue next-step xW prefetch. R3 had the prefetch before the
// drain, so every signal serially waited on a deep HBM load queue (~3-4us/step).
__global__ __launch_bounds__(256, 1) void lstm_kernel(const half_t* __restrict__ xw,
                                                      const half_t* __restrict__ UT,
                                                      half_t* __restrict__ hbuf,
                                                      const unsigned long long* __restrict__ mk,
                                                      float* __restrict__ out,
                                                      unsigned* __restrict__ cnt) {
    __shared__ half_t Ast[8192];   // 16 kk * 64 lanes * 8 halves, MFMA-frag order
    __shared__ half_t Pk[1024];    // h repack: [16 rows][64 units]
    int bx = blockIdx.x;
    int dir = bx >> 7;
    int rowg = (bx >> 3) & 15;
    int wgc = bx & 7;
    int tid = threadIdx.x;
    int w = tid >> 6, l = tid & 63;
    int q = l >> 4, cl = l & 15;
    int cg = wgc * 4 + w;           // col-group 0..31
    int ub = cg * 16;               // unit base (per wave)
    int ub0 = wgc * 64;             // unit base (per WG)
    int r0 = rowg * 16;             // sequence-row base

    // preload U B-frags into registers: bfrag[kk*4+cf], cf = gate
    half8 bfrag[64];
#pragma unroll
    for (int kk = 0; kk < 16; ++kk)
#pragma unroll
        for (int cf = 0; cf < 4; ++cf)
            bfrag[kk * 4 + cf] = *(const half8*)(UT + (size_t)(dir * 2048 + cf * 512 + ub + cl) * KDIM + kk * 32 + q * 8);

    // preload this thread's 4 rows' validity masks (128 bits each)
    unsigned long long mlo[4], mhi[4];
#pragma unroll
    for (int r = 0; r < 4; ++r) {
        int n = r0 + q * 4 + r;
        mlo[r] = mk[n * 2];
        mhi[r] = mk[n * 2 + 1];
    }

    float cs[4] = {0.f, 0.f, 0.f, 0.f};
    float hs[4] = {0.f, 0.f, 0.f, 0.f};
    unsigned* cptr = cnt + (dir * 16 + rowg) * 16;   // 64B-strided counters
    int colb = dir * 2048 + ub + cl;

    // prefetch xW for t=0 (bias already baked in)
    half_t xv[4][4];
    {
        int tIdx = dir ? 127 : 0;
#pragma unroll
        for (int r = 0; r < 4; ++r) {
            size_t ro = ((size_t)(r0 + q * 4 + r) * TLEN + tIdx) * NCOL;
#pragma unroll
            for (int g = 0; g < 4; ++g)
                xv[g][r] = xw[ro + colb + g * 512];
        }
    }

#pragma unroll 1
    for (int t = 0; t < TLEN; ++t) {
        int tIdx = dir ? (127 - t) : t;
        int rpar = t & 1, wpar = rpar ^ 1;
        if (t > 0) {
            if (tid == 0) {
                while (__hip_atomic_load(cptr, __ATOMIC_RELAXED, __HIP_MEMORY_SCOPE_AGENT) < (unsigned)(32 * t))
                    __builtin_amdgcn_s_sleep(1);
            }
            __syncthreads();
        }
        // stage h rows r0..r0+15 into LDS in frag order (coherent 8B loads)
        const half_t* hsrc = hbuf + (size_t)(dir * 2 + rpar) * NSEQ * UNITSZ;
#pragma unroll
        for (int cc = 0; cc < 4; ++cc) {
            int c = tid + cc * 256;            // 1024 chunks of 16B
            int kk = c >> 6, ll = c & 63;
            int m = ll & 15, koff = kk * 32 + (ll >> 4) * 8;
            const half_t* sp = hsrc + (size_t)(r0 + m) * UNITSZ + koff;
            union { unsigned long long u[2]; half8 v; } cv;
            cv.u[0] = ld8c(sp);
            cv.u[1] = ld8c(sp + 4);
            *(half8*)(Ast + c * 8) = cv.v;
        }
        __syncthreads();
        // acc init from prefetched xW
        floatx4 a0, a1, a2, a3;
#pragma unroll
        for (int r = 0; r < 4; ++r) {
            a0[r] = (float)xv[0][r];
            a1[r] = (float)xv[1][r];
            a2[r] = (float)xv[2][r];
            a3[r] = (float)xv[3][r];
        }
        // z += h @ U
#pragma unroll
        for (int kk = 0; kk < 16; ++kk) {
            half8 af = *(const half8*)(Ast + (kk * 64 + l) * 8);
            a0 = __builtin_amdgcn_mfma_f32_16x16x32_f16(af, bfrag[kk * 4 + 0], a0, 0, 0, 0);
            a1 = __builtin_amdgcn_mfma_f32_16x16x32_f16(af, bfrag[kk * 4 + 1], a1, 0, 0, 0);
            a2 = __builtin_amdgcn_mfma_f32_16x16x32_f16(af, bfrag[kk * 4 + 2], a2, 0, 0, 0);
            a3 = __builtin_amdgcn_mfma_f32_16x16x32_f16(af, bfrag[kk * 4 + 3], a3, 0, 0, 0);
        }
        // gates + masked state update (mask from registers, zero vmem), repack h
#pragma unroll
        for (int r = 0; r < 4; ++r) {
            unsigned long long mw = (tIdx & 64) ? mhi[r] : mlo[r];
            bool keep = (mw >> (tIdx & 63)) & 1ull;
            float iv = sigm(a0[r]);
            float fv = sigm(a1[r]);
            float gv = tanhx(a2[r]);
            float ov = sigm(a3[r]);
            float cn = fv * cs[r] + iv * gv;
            float hn = ov * tanhx(cn);
            if (keep) { cs[r] = cn; hs[r] = hn; }
            Pk[(q * 4 + r) * 64 + w * 16 + cl] = (half_t)hs[r];
        }
        __syncthreads();
        // packed coherent store: 1 x 8B per thread (16 rows x 64 units x 2B = 2KB/WG)
        half_t* hdst = hbuf + (size_t)(dir * 2 + wpar) * NSEQ * UNITSZ;
        {
            int prow = tid >> 4, pch = tid & 15;
            unsigned long long pv = *(const unsigned long long*)(Pk + prow * 64 + pch * 4);
            st8c(hdst + (size_t)(r0 + prow) * UNITSZ + ub0 + pch * 4, pv);
        }
        // release: only the pack store is outstanding -> cheap drain
        asm volatile("s_waitcnt vmcnt(0)" ::: "memory");
        if (l == 0)
            __hip_atomic_fetch_add(cptr, 1u, __ATOMIC_RELAXED, __HIP_MEMORY_SCOPE_AGENT);
        // NOW issue next-step xW prefetch: overlaps the next poll/stage phase
        if (t + 1 < TLEN) {
            int tN = dir ? (126 - t) : (t + 1);
#pragma unroll
            for (int r = 0; r < 4; ++r) {
                size_t ro = ((size_t)(r0 + q * 4 + r) * TLEN + tN) * NCOL;
#pragma unroll
                for (int g = 0; g < 4; ++g)
                    xv[g][r] = xw[ro + colb + g * 512];
            }
        }
    }
    // final output: out[n][dir*512 + unit]
#pragma unroll
    for (int r = 0; r < 4; ++r) {
        int n = r0 + q * 4 + r;
        out[(size_t)n * 1024 + dir * 512 + ub + cl] = hs[r];
    }
}

extern "C" void kernel_launch(void* const* d_in, const int* in_sizes, int n_in,
                              void* d_out, int out_size, void* d_ws, size_t ws_size,
                              hipStream_t stream) {
    const int*   x    = (const int*)d_in[0];
    const float* tab  = (const float*)d_in[1];
    const float* Wf   = (const float*)d_in[2];
    const float* Uf   = (const float*)d_in[3];
    const float* bf   = (const float*)d_in[4];
    const float* Wb   = (const float*)d_in[5];
    const float* Ub   = (const float*)d_in[6];
    const float* bb   = (const float*)d_in[7];
    float* out = (float*)d_out;

    char* ws = (char*)d_ws;
    half_t*   embf = (half_t*)(ws + OFF_EMB);
    half_t*   WT   = (half_t*)(ws + OFF_WT);
    half_t*   UT   = (half_t*)(ws + OFF_UT);
    half_t*   hbuf = (half_t*)(ws + OFF_HB);
    unsigned* cnt  = (unsigned*)(ws + OFF_CNT);
    unsigned long long* mkb = (unsigned long long*)(ws + OFF_MSK);
    half_t*   xw   = (half_t*)(ws + OFF_XW);
    unsigned* hbz  = (unsigned*)(ws + OFF_HB);   // zero range covers hbuf + cnt (contiguous)

    pack_kernel<<<2048, 256, 0, stream>>>(Wf, Uf, Wb, Ub, WT, UT);
    zero_kernel<<<1028, 256, 0, stream>>>(hbz);
    mask_kernel<<<256, 64, 0, stream>>>(x, mkb);
    gather_kernel<<<8192, 256, 0, stream>>>(x, tab, embf);
    gemm_kernel<<<8192, 256, 0, stream>>>(embf, WT, bf, bb, xw);
    lstm_kernel<<<256, 256, 0, stream>>>(xw, UT, hbuf, mkb, out, cnt);
}